// Round 1
// baseline (11.046 us; speedup 1.0000x reference)
//
#include <hip/hip_runtime.h>

// Analytical collapse of the 10-qubit circuit:
//
// The initial state RX(w0,xa) RX(w1,ya) |0..0> has exactly 4 nonzero basis
// amplitudes (product state on wires 0,1; wires 2..9 stay |0>). CNOTs only
// permute basis states (and keep the 4 states distinct: the CNOT chain is an
// invertible linear map over GF(2)); RZ gates are diagonal phases. Hence the
// 4 probabilities are fixed by the RX layer and ALL theta values are
// irrelevant to the measured output.
//
// The CNOT chain (control i -> target i+1, i = 0..8) maps bit vector b to its
// prefix-XOR. Applied 3x to (b0, b1, 0, ..., 0) the final bits are the
// period-4 pattern: bit0 = b0, bit1 = b0^b1, bit2 = b1, bit3 = 0, ...
// Only bits 0,1,2 are measured, giving Z-expectations:
//   e0 = cos(xa),  e1 = cos(xa)*cos(ya),  e2 = cos(ya)
// with xa = 2*pi*x0 - pi  =>  cos(xa) = -cos(2*pi*x0), same for ya.
// Output j is (e_j + 1) / 2.

#ifndef M_PI_F
#define M_PI_F 3.14159265358979323846f
#endif

__global__ __launch_bounds__(256) void qmodel_analytic_kernel(
    const float* __restrict__ x,   // (B, 2) row-major
    float* __restrict__ out,       // (B, 3) row-major
    int B)
{
    int i = blockIdx.x * blockDim.x + threadIdx.x;
    if (i >= B) return;

    float2 xv = reinterpret_cast<const float2*>(x)[i];

    // cos(2*pi*x - pi) = -cos(2*pi*x). Arguments are in [0, 2*pi) — small,
    // so even fast-math cosf is far inside the 2e-2 absmax threshold.
    float cx = -__cosf(2.0f * M_PI_F * xv.x);
    float cy = -__cosf(2.0f * M_PI_F * xv.y);

    out[i * 3 + 0] = 0.5f * (cx + 1.0f);
    out[i * 3 + 1] = 0.5f * (cx * cy + 1.0f);
    out[i * 3 + 2] = 0.5f * (cy + 1.0f);
}

extern "C" void kernel_launch(void* const* d_in, const int* in_sizes, int n_in,
                              void* d_out, int out_size, void* d_ws, size_t ws_size,
                              hipStream_t stream)
{
    const float* x = (const float*)d_in[0];   // (B, 2) float32
    // d_in[1] = theta (30 floats) — provably irrelevant to the output.
    float* out = (float*)d_out;               // (B, 3) float32

    int B = in_sizes[0] / 2;                  // 16384
    int block = 256;
    int grid = (B + block - 1) / block;       // 64 blocks
    qmodel_analytic_kernel<<<grid, block, 0, stream>>>(x, out, B);
}